// Round 1
// baseline (76928.632 us; speedup 1.0000x reference)
//
#include <hip/hip_runtime.h>

// TinyRNNPolicy: h_{t+1} = tanh(W h_t); action_t = tanh(mean(h_{t+1}[:2048]))
// Strategy: persistent grid-resident kernel. W (64 MiB fp32) lives in VGPRs:
// 256 blocks x 512 threads x 128 floats/thread. Each step: broadcast h (16 KiB)
// into LDS per CU, 128 FMAs/thread, LDS reduce (32 partials/row), tanh, write
// h_next to global, hand-rolled device-wide barrier (monotonic counter in ws).

#define N 4096
#define HALF 2048
#define BLOCKS 256
#define TPB 512
#define ROWS_PER_BLOCK 16     // 4096 rows / 256 blocks
#define CHUNK_COLS 128        // 4096 cols / 32 chunks
#define PAD 132               // chunk stride in LDS floats (conflict-free: 132%32=4)

// ws layout in 4-byte units (ws is re-poisoned to 0xAA each launch -> init kernel)
#define WS_CNT 0              // barrier counter (unsigned), monotonic
#define WS_ACC 256            // accum[out_size] readout partial sums
#define WS_HA  (256 + 4096)   // h ping buffer
#define WS_HB  (256 + 8192)   // h pong buffer

__global__ void rnn_init(const float* __restrict__ h0, float* __restrict__ ws, int n_out) {
    int i = blockIdx.x * blockDim.x + threadIdx.x;
    if (i == 0) ((unsigned*)ws)[WS_CNT] = 0u;
    if (i < n_out) ws[WS_ACC + i] = 0.0f;
    if (i < N) ws[WS_HA + i] = h0[i];
}

__device__ __forceinline__ float tanh_fast(float x) {
    // exact 0 at x==0 (expf(0)==1); clamp avoids inf/inf NaN
    x = fminf(fmaxf(x, -15.0f), 15.0f);
    float e = __expf(2.0f * x);
    return (e - 1.0f) / (e + 1.0f);
}

__global__ void __launch_bounds__(TPB, 2)
rnn_persistent(const float* __restrict__ W, const int* __restrict__ pns,
               float* __restrict__ out, float* __restrict__ ws) {
    const int b = blockIdx.x;
    const int t = threadIdx.x;
    const int row = t & 15;        // row within block's 16 rows
    const int chunk = t >> 4;      // 0..31, 128-col chunk
    const int grow = b * ROWS_PER_BLOCK + row;

    // ---- stage W slice into registers (one-time, ~64 MiB total from HBM) ----
    float w[CHUNK_COLS];
    {
        const float4* Wv = (const float4*)(W + (size_t)grow * N + (size_t)chunk * CHUNK_COLS);
#pragma unroll
        for (int i = 0; i < CHUNK_COLS / 4; ++i) {
            float4 v = Wv[i];
            w[4*i+0] = v.x; w[4*i+1] = v.y; w[4*i+2] = v.z; w[4*i+3] = v.w;
        }
    }

    const int n_steps = *pns;

    __shared__ float hs[32 * PAD];   // padded h broadcast buffer (~16.5 KiB)
    __shared__ float part[TPB];      // per-thread row partials

    unsigned* cnt = (unsigned*)ws + WS_CNT;
    float* accum = ws + WS_ACC;
    float* hA = ws + WS_HA;
    float* hB = ws + WS_HB;

    for (int s = 0; s < n_steps; ++s) {
        const float* __restrict__ hc = (s & 1) ? hB : hA;
        float*       hn              = (s & 1) ? hA : hB;

        // ---- stage h (4096 floats) into LDS, padded layout ----
        {
            const float4* hv4 = (const float4*)(hc + 8 * t);
            float4 a0 = hv4[0];
            float4 a1 = hv4[1];
            int base = (t >> 4) * PAD + 8 * (t & 15);  // chunk (8t)>>7 = t>>4
            float4* dst = (float4*)&hs[base];
            dst[0] = a0; dst[1] = a1;
        }
        __syncthreads();

        // ---- 128 FMAs: row dot-product partial over this thread's chunk ----
        // LDS reads: 16 lanes (rows) share each address -> broadcast; the 4
        // chunk-groups per wave land on disjoint 4-bank sets (PAD=132).
        float s0 = 0.f, s1 = 0.f, s2 = 0.f, s3 = 0.f;
        const int hb = chunk * PAD;
#pragma unroll
        for (int k = 0; k < CHUNK_COLS; k += 4) {
            float4 hv = *(const float4*)&hs[hb + k];
            s0 = fmaf(w[k+0], hv.x, s0);
            s1 = fmaf(w[k+1], hv.y, s1);
            s2 = fmaf(w[k+2], hv.z, s2);
            s3 = fmaf(w[k+3], hv.w, s3);
        }
        part[chunk * 16 + row] = (s0 + s1) + (s2 + s3);  // addr = 64w+l, conflict-free
        __syncthreads();

        // ---- reduce 32 chunk-partials per row, tanh, write h_next ----
        float hval = 0.0f;
        if (t < ROWS_PER_BLOCK) {
            float acc = 0.0f;
#pragma unroll
            for (int c = 0; c < 32; ++c) acc += part[c * 16 + t];  // banks distinct across 16 lanes
            hval = tanh_fast(acc);
            hn[b * ROWS_PER_BLOCK + t] = hval;
        }

        // ---- readout partial: sum of this block's 16 h values (rows < 2048) ----
        float v = hval;                       // lanes 16..63 contribute 0
        v += __shfl_down(v, 8);
        v += __shfl_down(v, 4);
        v += __shfl_down(v, 2);
        v += __shfl_down(v, 1);
        if (t == 0 && b < (BLOCKS / 2)) atomicAdd(accum + s, v);

        // ---- device-wide barrier: monotonic counter, release/acquire fences ----
        __syncthreads();   // compiler drains vmcnt before s_barrier -> wave stores done
        if (t == 0) {
            __threadfence();  // release: h_next + accum visible device-wide
            __hip_atomic_fetch_add(cnt, 1u, __ATOMIC_RELAXED, __HIP_MEMORY_SCOPE_AGENT);
            const unsigned target = (unsigned)(s + 1) * (unsigned)BLOCKS;
            unsigned spins = 0;
            while (__hip_atomic_load(cnt, __ATOMIC_RELAXED, __HIP_MEMORY_SCOPE_AGENT) < target) {
                __builtin_amdgcn_s_sleep(1);
                if (++spins > (1u << 16)) break;  // bailout: fail loud, don't hang
            }
            __threadfence();  // acquire: invalidate L1/L2 so fresh h is read
        }
        __syncthreads();

        // ---- finalize action for this step (all partials visible post-barrier) ----
        if (b == 0 && t == 0) {
            out[s] = tanh_fast(accum[s] * (1.0f / (float)HALF));
        }
    }
}

extern "C" void kernel_launch(void* const* d_in, const int* in_sizes, int n_in,
                              void* d_out, int out_size, void* d_ws, size_t ws_size,
                              hipStream_t stream) {
    const float* W  = (const float*)d_in[0];
    const float* h0 = (const float*)d_in[1];
    const int*  pns = (const int*)d_in[2];
    float* out = (float*)d_out;
    float* ws  = (float*)d_ws;

    int n_init = out_size > N ? out_size : N;
    rnn_init<<<(n_init + 255) / 256, 256, 0, stream>>>(h0, ws, out_size);
    rnn_persistent<<<BLOCKS, TPB, 0, stream>>>(W, pns, out, ws);
}

// Round 2
// 18673.158 us; speedup vs baseline: 4.1197x; 4.1197x over previous
//
#include <hip/hip_runtime.h>

// TinyRNNPolicy: h_{t+1} = tanh(W h_t); action_t = tanh(mean(h_{t+1}[:2048]))
//
// R2 design: persistent kernel, 256 blocks x 1024 threads (1 block/CU).
// W slice (16 rows x 4096) lives in VGPRs: 64 floats/thread.
// All cross-block data (h ping-pong, barrier flags, readout partials) moves
// via relaxed AGENT-scope atomic ld/st (sc0 sc1 -> coherence point), so NO
// threadfence / L2 writeback is ever needed. Barrier = per-block flag store
// + all-blocks poll with __syncthreads_and. Readout (tanh(mean(h[:2048])))
// is deferred: per-step per-block partials are written once to ws, and all
// n_steps outputs are computed in parallel after the main loop.

#define N 4096
#define HALF 2048
#define BLOCKS 256
#define TPB 1024
#define RPB 16        // rows per block (4096/256)
#define CCOLS 64      // cols per thread-chunk
#define NCH 64        // chunks per row-group (4096/64)
#define PAD 68        // LDS chunk stride (68%32==4 -> conflict-free groups)

// ws layout (dword offsets). ws re-poisoned 0xAA each launch -> init kernel.
#define WS_FLAGS 0            // 256 flags, stride 16 dwords (64B lines)
#define WS_HA    4096         // h ping
#define WS_HB    8192         // h pong
#define WS_ACC   12288        // accum[out_size] (fallback path only)
#define WS_PART  16384        // parts[n_steps*128] (big path)

__device__ __forceinline__ float agent_ld(const float* p) {
    return __hip_atomic_load(p, __ATOMIC_RELAXED, __HIP_MEMORY_SCOPE_AGENT);
}
__device__ __forceinline__ void agent_st(float* p, float v) {
    __hip_atomic_store(p, v, __ATOMIC_RELAXED, __HIP_MEMORY_SCOPE_AGENT);
}
__device__ __forceinline__ unsigned agent_ldu(const unsigned* p) {
    return __hip_atomic_load(p, __ATOMIC_RELAXED, __HIP_MEMORY_SCOPE_AGENT);
}
__device__ __forceinline__ void agent_stu(unsigned* p, unsigned v) {
    __hip_atomic_store(p, v, __ATOMIC_RELAXED, __HIP_MEMORY_SCOPE_AGENT);
}

__device__ __forceinline__ float tanh_fast(float x) {
    x = fminf(fmaxf(x, -15.0f), 15.0f);   // clamp avoids inf/inf
    float e = __expf(2.0f * x);
    return (e - 1.0f) / (e + 1.0f);       // exact 0 at x==0
}

__global__ void rnn_init(const float* __restrict__ h0, float* __restrict__ ws, int n_out) {
    int i = blockIdx.x * blockDim.x + threadIdx.x;
    if (i < BLOCKS * 16) agent_stu((unsigned*)ws + WS_FLAGS + i, 0u);
    if (i < n_out) agent_st(ws + WS_ACC + i, 0.0f);
    if (i < N) agent_st(ws + WS_HA + i, h0[i]);
}

__global__ void __launch_bounds__(TPB, 4)
rnn_persistent(const float* __restrict__ W, const int* __restrict__ pns,
               float* __restrict__ out, float* __restrict__ ws, int big) {
    const int b = blockIdx.x;
    const int t = threadIdx.x;
    const int row = t & 15;        // row within block's 16 rows
    const int chunk = t >> 4;      // 0..63, 64-col chunk
    const int grow = b * RPB + row;

    // ---- one-time: W slice into registers (64 floats/thread) ----
    float w[CCOLS];
    {
        const float4* Wv = (const float4*)(W + (size_t)grow * N + (size_t)chunk * CCOLS);
#pragma unroll
        for (int i = 0; i < CCOLS / 4; ++i) {
            float4 v = Wv[i];
            w[4*i+0] = v.x; w[4*i+1] = v.y; w[4*i+2] = v.z; w[4*i+3] = v.w;
        }
    }

    const int n_steps = *pns;

    __shared__ float hs[NCH * PAD];   // padded h broadcast (~17 KiB)
    __shared__ float part[TPB];       // per-thread dot partials

    unsigned* flags = (unsigned*)ws + WS_FLAGS;
    float* hA    = ws + WS_HA;
    float* hB    = ws + WS_HB;
    float* accum = ws + WS_ACC;
    float* parts = ws + WS_PART;

    for (int s = 0; s < n_steps; ++s) {
        const float* hc = (s & 1) ? hB : hA;
        float*       hn = (s & 1) ? hA : hB;

        // ---- stage h into LDS: 4 agent-scope dword loads per thread ----
        {
            float h0_ = agent_ld(hc + 4*t + 0);
            float h1_ = agent_ld(hc + 4*t + 1);
            float h2_ = agent_ld(hc + 4*t + 2);
            float h3_ = agent_ld(hc + 4*t + 3);
            // element 4t lands at chunk (4t)>>6 = t>>4, offset 4*(t&15)
            int base = (t >> 4) * PAD + 4 * (t & 15);
            *(float4*)&hs[base] = make_float4(h0_, h1_, h2_, h3_);
        }
        __syncthreads();

        // ---- 64 FMAs over this thread's chunk (16-lane broadcast reads) ----
        float s0 = 0.f, s1 = 0.f, s2 = 0.f, s3 = 0.f;
        const int hb = chunk * PAD;
#pragma unroll
        for (int k = 0; k < CCOLS; k += 4) {
            float4 hv = *(const float4*)&hs[hb + k];
            s0 = fmaf(w[k+0], hv.x, s0);
            s1 = fmaf(w[k+1], hv.y, s1);
            s2 = fmaf(w[k+2], hv.z, s2);
            s3 = fmaf(w[k+3], hv.w, s3);
        }
        part[chunk * 16 + row] = (s0 + s1) + (s2 + s3);
        __syncthreads();

        // ---- reduce 64 chunk-partials per row, tanh, publish h_next ----
        float hval = 0.0f;
        if (t < RPB) {
            float acc = 0.0f;
#pragma unroll
            for (int c = 0; c < NCH; ++c) acc += part[c * 16 + t];
            hval = tanh_fast(acc);
            agent_st(hn + b * RPB + t, hval);
        }

        // ---- readout partial: sum of this block's 16 h values ----
        float v = (t < RPB) ? hval : 0.0f;   // wave 0 only carries data
        v += __shfl_down(v, 8);
        v += __shfl_down(v, 4);
        v += __shfl_down(v, 2);
        v += __shfl_down(v, 1);
        if (t == 0 && b < (BLOCKS / 2)) {
            if (big) agent_st(parts + (size_t)s * 128 + b, v);  // write-once slot
            else     atomicAdd(accum + s, v);                   // fallback
        }

        // ---- device barrier: flag store + poll, NO fences ----
        __syncthreads();   // each wave drains vmcnt before s_barrier -> all stores complete
        if (t == 0) agent_stu(flags + b * 16, (unsigned)(s + 1));
        {
            const unsigned tgt = (unsigned)(s + 1);
            int ready;
            unsigned spins = 0;
            do {
                int ok = 1;
                if (t < BLOCKS) ok = (agent_ldu(flags + t * 16) >= tgt);
                ready = __syncthreads_and(ok);
                if (!ready) {
                    __builtin_amdgcn_s_sleep(1);
                    if (++spins > (1u << 20)) break;   // fail loud, don't hang
                }
            } while (!ready);
        }

        if (!big && b == 0 && t == 0)
            out[s] = tanh_fast(agent_ld(accum + s) * (1.0f / (float)HALF));
    }

    // ---- big path: all outputs computed in parallel after the loop ----
    if (big) {
        const int l = t & 63;
        for (int ss = b * 16 + (t >> 6); ss < n_steps; ss += BLOCKS * 16) {
            float v = agent_ld(parts + (size_t)ss * 128 + l)
                    + agent_ld(parts + (size_t)ss * 128 + 64 + l);
            v += __shfl_down(v, 32);
            v += __shfl_down(v, 16);
            v += __shfl_down(v, 8);
            v += __shfl_down(v, 4);
            v += __shfl_down(v, 2);
            v += __shfl_down(v, 1);
            if (l == 0) out[ss] = tanh_fast(v * (1.0f / (float)HALF));
        }
    }
}

extern "C" void kernel_launch(void* const* d_in, const int* in_sizes, int n_in,
                              void* d_out, int out_size, void* d_ws, size_t ws_size,
                              hipStream_t stream) {
    const float* W  = (const float*)d_in[0];
    const float* h0 = (const float*)d_in[1];
    const int*  pns = (const int*)d_in[2];
    float* out = (float*)d_out;
    float* ws  = (float*)d_ws;

    // out_size == n_steps (reference returns [n_steps]); big path needs
    // parts[n_steps*128] floats after WS_PART dwords.
    size_t need = ((size_t)WS_PART + (size_t)out_size * 128) * 4;
    int big = (ws_size >= need) ? 1 : 0;

    int n_init = out_size > N ? out_size : N;
    rnn_init<<<(n_init + 255) / 256, 256, 0, stream>>>(h0, ws, out_size);
    rnn_persistent<<<BLOCKS, TPB, 0, stream>>>(W, pns, out, ws, big);
}

// Round 3
// 16949.036 us; speedup vs baseline: 4.5388x; 1.1017x over previous
//
#include <hip/hip_runtime.h>

// TinyRNNPolicy: h_{t+1} = tanh(W h_t); action_t = tanh(mean(h_{t+1}[:2048]))
//
// R3: persistent kernel, 256 blocks x 1024 threads (1 block/CU).
// W slice (16 rows x 4096) pinned in VGPRs (64 floats/thread) via asm
// register barrier -- R2's VGPR_Count=56 proved the compiler rematerialized
// the W loads into the step loop (re-reading 64 MiB/step from L2/L3, the
// dominant cost). Cross-block traffic via relaxed agent-scope atomics
// (no fences). Barrier: wave-0 release (vmcnt drain + flag store) +
// per-lane flag spin (t<256) + one __syncthreads.

#define N 4096
#define HALF 2048
#define BLOCKS 256
#define TPB 1024
#define RPB 16        // rows per block
#define CCOLS 64      // cols per thread-chunk
#define NCH 64        // chunks (4096/64)
#define PAD 68        // LDS chunk stride (68%32==4 -> conflict-free groups)

// ws layout (dword offsets); ws re-poisoned 0xAA each launch -> init kernel.
#define WS_FLAGS 0            // 256 flags, stride 16 dwords (64B lines)
#define WS_HA    4096         // h ping
#define WS_HB    8192         // h pong
#define WS_ACC   12288        // accum[out_size] (fallback path only)
#define WS_PART  16384        // parts[n_steps*128] (big path)

__device__ __forceinline__ float agent_ld(const float* p) {
    return __hip_atomic_load(p, __ATOMIC_RELAXED, __HIP_MEMORY_SCOPE_AGENT);
}
__device__ __forceinline__ void agent_st(float* p, float v) {
    __hip_atomic_store(p, v, __ATOMIC_RELAXED, __HIP_MEMORY_SCOPE_AGENT);
}
__device__ __forceinline__ unsigned agent_ldu(const unsigned* p) {
    return __hip_atomic_load(p, __ATOMIC_RELAXED, __HIP_MEMORY_SCOPE_AGENT);
}
__device__ __forceinline__ void agent_stu(unsigned* p, unsigned v) {
    __hip_atomic_store(p, v, __ATOMIC_RELAXED, __HIP_MEMORY_SCOPE_AGENT);
}

__device__ __forceinline__ float tanh_fast(float x) {
    x = fminf(fmaxf(x, -15.0f), 15.0f);   // clamp avoids inf/inf
    float e = __expf(2.0f * x);
    return (e - 1.0f) / (e + 1.0f);       // exact 0 at x==0
}

__global__ void rnn_init(const float* __restrict__ h0, float* __restrict__ ws, int n_out) {
    int i = blockIdx.x * blockDim.x + threadIdx.x;
    if (i < BLOCKS * 16) agent_stu((unsigned*)ws + WS_FLAGS + i, 0u);
    if (i < n_out) agent_st(ws + WS_ACC + i, 0.0f);
    if (i < N) agent_st(ws + WS_HA + i, h0[i]);
}

__global__ void __launch_bounds__(TPB, 4)
rnn_persistent(const float* __restrict__ W, const int* __restrict__ pns,
               float* __restrict__ out, float* __restrict__ ws, int big) {
    const int b = blockIdx.x;
    const int t = threadIdx.x;
    const int lane = t & 63;
    const int wave = t >> 6;       // 0..15
    const int row = t & 15;        // row within block's 16 rows
    const int chunk = t >> 4;      // 0..63, 64-col chunk
    const int grow = b * RPB + row;

    // ---- one-time: W slice into registers, then PIN with asm barrier ----
    float w[CCOLS];
    {
        const float4* Wv = (const float4*)(W + (size_t)grow * N + (size_t)chunk * CCOLS);
#pragma unroll
        for (int i = 0; i < CCOLS / 4; ++i) {
            float4 v = Wv[i];
            w[4*i+0] = v.x; w[4*i+1] = v.y; w[4*i+2] = v.z; w[4*i+3] = v.w;
        }
    }
#pragma unroll
    for (int i = 0; i < CCOLS; ++i) asm volatile("" : "+v"(w[i]));  // pin: no remat

    const int n_steps = *pns;

    __shared__ float hs[NCH * PAD];   // padded h broadcast (~17.4 KiB)
    __shared__ float part[256];       // 16 waves x 16 rows

    unsigned* flags = (unsigned*)ws + WS_FLAGS;
    float* hA    = ws + WS_HA;
    float* hB    = ws + WS_HB;
    float* accum = ws + WS_ACC;
    float* parts = ws + WS_PART;

    for (int s = 0; s < n_steps; ++s) {
        const float* hc = (s & 1) ? hB : hA;
        float*       hn = (s & 1) ? hA : hB;

        // ---- stage h into LDS (agent loads bypass L1; padded layout) ----
        {
            float h0_ = agent_ld(hc + 4*t + 0);
            float h1_ = agent_ld(hc + 4*t + 1);
            float h2_ = agent_ld(hc + 4*t + 2);
            float h3_ = agent_ld(hc + 4*t + 3);
            int base = (t >> 4) * PAD + 4 * (t & 15);
            *(float4*)&hs[base] = make_float4(h0_, h1_, h2_, h3_);
        }
        __syncthreads();

        // ---- 64 FMAs over this thread's chunk (16-lane broadcast reads) ----
        float s0 = 0.f, s1 = 0.f, s2 = 0.f, s3 = 0.f;
        const int hb = chunk * PAD;
#pragma unroll
        for (int k = 0; k < CCOLS; k += 4) {
            float4 hv = *(const float4*)&hs[hb + k];
            s0 = fmaf(w[k+0], hv.x, s0);
            s1 = fmaf(w[k+1], hv.y, s1);
            s2 = fmaf(w[k+2], hv.z, s2);
            s3 = fmaf(w[k+3], hv.w, s3);
        }
        float v = (s0 + s1) + (s2 + s3);

        // ---- intra-wave reduce: wave's 4 chunks -> lanes 0..15 (16 rows) ----
        v += __shfl_down(v, 32);
        v += __shfl_down(v, 16);
        if (lane < 16) part[wave * 16 + lane] = v;
        __syncthreads();

        // ---- wave 0: final reduce (16 partials/row), tanh, publish, flag ----
        if (wave == 0) {
            float hval = 0.0f;
            if (t < RPB) {
                float acc = 0.0f;
#pragma unroll
                for (int c = 0; c < 16; ++c) acc += part[c * 16 + t];
                hval = tanh_fast(acc);
                agent_st(hn + b * RPB + t, hval);    // one 64B line
            }
            // readout partial: sum of this block's 16 h values
            float r = (t < RPB) ? hval : 0.0f;
            r += __shfl_down(r, 8);
            r += __shfl_down(r, 4);
            r += __shfl_down(r, 2);
            r += __shfl_down(r, 1);
            if (t == 0 && b < (BLOCKS / 2)) {
                if (big) agent_st(parts + (size_t)s * 128 + b, r);
                else     atomicAdd(accum + s, r);
            }
            // release: drain this wave's global stores, then publish flag
            asm volatile("s_waitcnt vmcnt(0)" ::: "memory");
            if (t == 0) agent_stu(flags + b * 16, (unsigned)(s + 1));
        }

        // ---- device barrier: per-lane spin on one flag each, then join ----
        if (t < BLOCKS) {
            const unsigned tgt = (unsigned)(s + 1);
            unsigned spins = 0;
            while (agent_ldu(flags + t * 16) < tgt) {
                __builtin_amdgcn_s_sleep(1);
                if (++spins > (1u << 22)) break;   // fail loud, don't hang
            }
        }
        __syncthreads();

        if (!big && b == 0 && t == 0)
            out[s] = tanh_fast(agent_ld(accum + s) * (1.0f / (float)HALF));
    }

    // ---- big path: all outputs computed in parallel after the loop ----
    if (big) {
        const int l = t & 63;
        for (int ss = b * 16 + (t >> 6); ss < n_steps; ss += BLOCKS * 16) {
            float v = agent_ld(parts + (size_t)ss * 128 + l)
                    + agent_ld(parts + (size_t)ss * 128 + 64 + l);
            v += __shfl_down(v, 32);
            v += __shfl_down(v, 16);
            v += __shfl_down(v, 8);
            v += __shfl_down(v, 4);
            v += __shfl_down(v, 2);
            v += __shfl_down(v, 1);
            if (l == 0) out[ss] = tanh_fast(v * (1.0f / (float)HALF));
        }
    }
}

extern "C" void kernel_launch(void* const* d_in, const int* in_sizes, int n_in,
                              void* d_out, int out_size, void* d_ws, size_t ws_size,
                              hipStream_t stream) {
    const float* W  = (const float*)d_in[0];
    const float* h0 = (const float*)d_in[1];
    const int*  pns = (const int*)d_in[2];
    float* out = (float*)d_out;
    float* ws  = (float*)d_ws;

    size_t need = ((size_t)WS_PART + (size_t)out_size * 128) * 4;
    int big = (ws_size >= need) ? 1 : 0;

    int n_init = out_size > N ? out_size : N;
    rnn_init<<<(n_init + 255) / 256, 256, 0, stream>>>(h0, ws, out_size);
    rnn_persistent<<<BLOCKS, TPB, 0, stream>>>(W, pns, out, ws, big);
}